// Round 17
// baseline (340.546 us; speedup 1.0000x reference)
//
#include <hip/hip_runtime.h>
#include <hip/hip_bf16.h>

// ============================================================================
// Head: K=x@Wk^T, Q=x@Wq^T, V=x@Wv^T, causal softmax(QK^T/8)@V
// B=4, T=4096, D=1024, H=64. fp32 I/O, bf16 MFMA compute.
//
// R22 = R21 resubmit (round 16 died to broker capacity, never measured).
// R21 = R20 (verified 339.4us best; attn 188.9, gemm+cvt ~150.5) + ONE
// change: gemm_all __launch_bounds__(256,2) -> (256,3).
//  Why: gemm_all (~130us, ~300 TF) matches the m97-structure's measured
//  value at this size (m102: 320 TF @ N=2048) -> latency/overhead bound,
//  not BW (R20's XCD remap: only -4us). Its VGPR count was never profiled;
//  (256,2) lets the allocator relax past 128 regs -> possibly only
//  2 blocks/CU in a latency-sensitive 2-barrier loop. (256,3) caps ~170
//  regs (need ~115-120: acc 64 AGPR + af/bfr 32 + addressing) -> no spill
//  risk, guarantees 3 blocks/CU. Worst case: allocator was already <=128
//  and this is a no-op. attn_fa/cvt byte-identical to R20.
//
// FENCED (R6=NaN / R11=3.6e5): {v_cvt_pk_bf16_f32 asm, __builtin_amdgcn_exp2f,
// s_setprio} in attn_fa — register/LDS corruption at the 128-reg wall.
// Dead: V-in-registers (R10 spills); 64-row 4-wave blocks (R9 drain-out);
// more waves (R13/R14: +50% occupancy, 0% speedup); attn micro-opts
// converged (R13 0%, R15 +7%, R17 0%); gemm L3-BW theory (R20: -4us only).
// ============================================================================

typedef __attribute__((ext_vector_type(8))) short bf16x8;   // 8 bf16, 4 VGPRs
typedef __attribute__((ext_vector_type(4))) float f32x4;

typedef unsigned short u16;
typedef unsigned int u32;

__device__ inline u16 f2bf(float f) {
    u32 u = __builtin_bit_cast(u32, f);
    u = (u + 0x7fff + ((u >> 16) & 1)) >> 16;   // RNE
    return (u16)u;
}

__device__ inline u32 pkbf(float a, float b) {  // bf16(a) | bf16(b)<<16
    return (u32)f2bf(a) | ((u32)f2bf(b) << 16);
}

__device__ inline void g2lds16(const void* g, void* l) {
    __builtin_amdgcn_global_load_lds(
        (const __attribute__((address_space(1))) unsigned int*)g,
        (__attribute__((address_space(3))) unsigned int*)l, 16, 0, 0);
}

// Fragment-tile addressing (16 rows x 32 k, 512 u16 = 1KB per tile):
//   element (r, k): u16 idx = ((r&15) + ((k>>3)&3)*16)*8 + (k&7)
// A-frag (m=lane&15, k=quad*8+j) and B-frag (n=lane&15, k=quad*8+j) reads are
// both "base + lane*16B" -> coalesced global / conflict-free LDS.

// ----------------------------------------------------------------------------
__global__ void cvt_x(const float* __restrict__ src, u16* __restrict__ dst,
                      int n) {
    const int i = (blockIdx.x * blockDim.x + threadIdx.x) * 8;
    if (i + 7 < n) {
        const float4 a = *(const float4*)(src + i);
        const float4 b = *(const float4*)(src + i + 4);
        u32 r[4];
        r[0] = pkbf(a.x, a.y);
        r[1] = pkbf(a.z, a.w);
        r[2] = pkbf(b.x, b.y);
        r[3] = pkbf(b.z, b.w);
        *(uint4*)(dst + i) = *(const uint4*)r;
    }
}

// Fused weight convert: Wk (1x), Wq (x 0.125*log2e), Wv (1x).
__global__ void cvt_w(const float* __restrict__ Wk, const float* __restrict__ Wq,
                      const float* __restrict__ Wv,
                      u16* __restrict__ Wkb, u16* __restrict__ Wqb,
                      u16* __restrict__ Wvb, float qscale) {
    const int i = (blockIdx.x * blockDim.x + threadIdx.x) * 8;
    const float* src; u16* dst; int j; float s = 1.0f;
    if (i < 65536)        { src = Wk; dst = Wkb; j = i; }
    else if (i < 131072)  { src = Wq; dst = Wqb; j = i - 65536; s = qscale; }
    else                  { src = Wv; dst = Wvb; j = i - 131072; }
    const float4 a = *(const float4*)(src + j);
    const float4 b = *(const float4*)(src + j + 4);
    u32 r[4];
    r[0] = pkbf(a.x * s, a.y * s);
    r[1] = pkbf(a.z * s, a.w * s);
    r[2] = pkbf(b.x * s, b.y * s);
    r[3] = pkbf(b.z * s, b.w * s);
    *(uint4*)(dst + j) = *(const uint4*)r;
}

// ----------------------------------------------------------------------------
// GEMM body: C = A[M][K] @ Bsel[N][K]^T, bf16, fp32 accum, 128x128, BK=64.
// lda = ldb = K = 1024. Outputs frag-tiled (MODE 1: Qf/Kf, MODE 2: Vf).
// ----------------------------------------------------------------------------
template <int MODE>
__device__ __forceinline__ void gemm_body(
    int m0, int n0,
    const u16* __restrict__ A,
    const u16* __restrict__ B0, const u16* __restrict__ B1, int nsplit,
    u16* __restrict__ D0, u16* __restrict__ D1,
    u16* Alds, u16* Blds)
{
    const int tid  = threadIdx.x;
    const int lane = tid & 63, w = tid >> 6;
    const int quad = lane >> 4, l15 = lane & 15;
    const int wr = w >> 1, wc = w & 1;
    const int mrow0 = wr * 64, ncol0 = wc * 64;

    f32x4 acc[4][4] = {};

    const int srow = (lane >> 3);
    const int scol = (lane & 7) * 8;

    for (int k0 = 0; k0 < 1024; k0 += 64) {
        __syncthreads();
#pragma unroll
        for (int c = 0; c < 4; ++c) {
            const int chunk = c * 4 + w;
            const int row = chunk * 8 + srow;
            const u16* ga = A + (size_t)(m0 + row) * 1024 + k0 + scol;
            g2lds16(ga, &Alds[chunk * 512]);
            const int brow = n0 + row;
            const u16* gb = (brow < nsplit ? B0 + (size_t)brow * 1024
                                           : B1 + (size_t)(brow - nsplit) * 1024)
                            + k0 + scol;
            g2lds16(gb, &Blds[chunk * 512]);
        }
        __syncthreads();

#pragma unroll
        for (int kk = 0; kk < 64; kk += 32) {
            bf16x8 af[4], bfr[4];
#pragma unroll
            for (int mb = 0; mb < 4; ++mb)
                af[mb] = *(const bf16x8*)&Alds[(mrow0 + mb * 16 + l15) * 64 + kk + quad * 8];
#pragma unroll
            for (int nb = 0; nb < 4; ++nb)
                bfr[nb] = *(const bf16x8*)&Blds[(ncol0 + nb * 16 + l15) * 64 + kk + quad * 8];
#pragma unroll
            for (int mb = 0; mb < 4; ++mb)
#pragma unroll
                for (int nb = 0; nb < 4; ++nb)
                    acc[mb][nb] = __builtin_amdgcn_mfma_f32_16x16x32_bf16(
                        af[mb], bfr[nb], acc[mb][nb], 0, 0, 0);
        }
    }

    // epilogue: C/D layout col=lane&15, row=quad*4+reg
#pragma unroll
    for (int mb = 0; mb < 4; ++mb)
#pragma unroll
        for (int nb = 0; nb < 4; ++nb)
#pragma unroll
            for (int r = 0; r < 4; ++r) {
                const int row = m0 + mrow0 + mb * 16 + quad * 4 + r;
                const int col = n0 + ncol0 + nb * 16 + l15;
                const u16 v = f2bf(acc[mb][nb][r]);
                if (MODE == 1) {
                    const int h = col & 63;
                    u16* dst = (col < 64) ? D0 : D1;
                    const size_t idx = (size_t)((row >> 4) * 2 + (h >> 5)) * 512
                                     + ((row & 15) + ((h >> 3) & 3) * 16) * 8
                                     + (h & 7);
                    dst[idx] = v;
                } else {
                    const size_t idx = (size_t)((row >> 4) * 512 + (col >> 5)) * 512
                                     + ((row & 15) + ((col >> 3) & 3) * 16) * 8
                                     + (col & 7);
                    D0[idx] = v;
                }
            }
}

// Combined GEMM dispatch: blocks [0,128) -> QK projection, [128,1152) -> Vt.
// MODE2 block->tile remap for XCD/L2 locality: g=dd&7, j=dd>>3,
// m0=(j&7)*128, n0=(g*16+(j>>3))*128. launch_bounds (256,3): cap ~170
// regs/wave (need ~120) -> guarantee 3 blocks/CU for the K-loop convoy.
__global__ __launch_bounds__(256, 3) void gemm_all(
    const u16* __restrict__ xb,
    const u16* __restrict__ Wqb, const u16* __restrict__ Wkb,
    const u16* __restrict__ Wvb,
    u16* __restrict__ Qf, u16* __restrict__ Kf, u16* __restrict__ Vf)
{
    __shared__ u16 Alds[128 * 64];
    __shared__ u16 Blds[128 * 64];
    const int d = blockIdx.x;
    if (d < 128) {
        gemm_body<1>(d * 128, 0, xb, Wqb, Wkb, 64, Qf, Kf, Alds, Blds);
    } else {
        const int dd = d - 128;
        const int g = dd & 7, j = dd >> 3;
        gemm_body<2>((j & 7) * 128, (g * 16 + (j >> 3)) * 128, Wvb, xb, xb,
                     1 << 30, Vf, nullptr, Alds, Blds);
    }
}

// ----------------------------------------------------------------------------
// Flash attention, no-max softmax, es-split P handoff, software-pipelined.
// grid (128,4) flat d: g=d>>4, qt = g<16 ? 31-g : g-16 (complementary pairs),
// e0 = ((d>>2)&3)*256, b = d&3. Block 1024 thr (16 waves): wave w ->
// qs=w>>1 (16 q rows), es=w&1 (32 of the 64 s-cols in computeP; 128 e cols
// in PV). s-tile = 64: ntiles = 2qt+2. Iter order: barrier -> stageV(it+1)
// -> loadK(it+1) -> PV(it) -> computeP(it+1).
// computeP uses SWAPPED mfma(K,Q): lane holds P[q=l15][s=quad*4+r], so the
// 4 values are consecutive in a Plds row -> one ds_write_b64 per strip.
// ----------------------------------------------------------------------------
__global__ __launch_bounds__(1024, 4) void attn_fa(
    const u16* __restrict__ Qf,
    const u16* __restrict__ Kf,
    const u16* __restrict__ Vf,
    float* __restrict__ Out)
{
    __shared__ u16 Vlds[2][32 * 512];   // 2 x 32KB (e=256, s=64)
    __shared__ u16 Plds[2][128 * 72];   // 2 x 18KB block-shared P, row-pad 72

    const int tid  = threadIdx.x;
    const int lane = tid & 63, w = tid >> 6;      // w in [0,16)
    const int quad = lane >> 4, l15 = lane & 15;

    const int d  = blockIdx.y * 128 + blockIdx.x;
    const int g  = d >> 4;
    const int qt = (g < 16) ? (31 - g) : (g - 16);
    const int e0 = ((d >> 2) & 3) * 256;
    const int b  = d & 3;
    const int bt0 = b * 4096;

    const int qs = w >> 1, es = w & 1;            // qs in [0,8): 16 rows each
    const int qrow0 = qt * 128 + qs * 16;

    // Q A-frags (persistent, log2-domain scaled): one 16-row tile, K=64
    bf16x8 qf[2];
    {
        const int btile = (bt0 + qrow0) >> 4;
#pragma unroll
        for (int kk = 0; kk < 2; ++kk)
            qf[kk] = *(const bf16x8*)&Qf[(size_t)(btile * 2 + kk) * 512 + lane * 8];
    }

    // ones B-fragment for row-sum accumulation (bf16 1.0 = 0x3F80)
    const short o = (short)0x3F80;
    const bf16x8 ones = {o, o, o, o, o, o, o, o};

    f32x4 acc[8] = {};      // O accumulator [nb_e]
    f32x4 accl = {};        // row-sum accumulator

    const int ntiles = 2 * qt + 2;      // s-tiles of 64
    const int qlim = qrow0 + 15;        // wave active for tile it iff it*64 <= qlim

    // ---- stage V tile `it` (64 s-cols) into Vlds[buf]: 2KB per wave ----
    auto stageV = [&](int buf, int it) {
        const int ct0 = (bt0 >> 5) + it * 2;
#pragma unroll
        for (int h = 0; h < 2; ++h)
            g2lds16(&Vf[(size_t)(((e0 >> 4) + w) * 512 + ct0 + h) * 512 + lane * 8],
                    &Vlds[buf][(h * 16 + w) * 512]);
    };

    // ---- load this wave's K quarter for tile `jt` (4 x b128 global) ----
    auto loadK = [&](int jt, bf16x8* kf) {
#pragma unroll
        for (int cc = 0; cc < 2; ++cc)
#pragma unroll
            for (int kk = 0; kk < 2; ++kk) {
                const int kt = ((bt0 + jt * 64 + es * 32 + cc * 16) >> 4) * 2 + kk;
                kf[cc * 2 + kk] = *(const bf16x8*)&Kf[(size_t)kt * 512 + lane * 8];
            }
    };

    // ---- compute this wave's (16q x 32s) strip of P(jt) into Plds[jt&1] ----
    // SWAPPED mfma(K,Q): D[m=s][n=q] -> lane (quad,l15) holds
    // P[q=qrow0+l15][s=c0+quad*4+r], 4 consecutive s in one Plds row.
    auto computeP = [&](int jt, const bf16x8* kf) {
        const int s0 = jt * 64;
#pragma unroll
        for (int cc = 0; cc < 2; ++cc) {
            f32x4 sf = {};
#pragma unroll
            for (int kk = 0; kk < 2; ++kk)
                sf = __builtin_amdgcn_mfma_f32_16x16x32_bf16(
                    kf[cc * 2 + kk], qf[kk], sf, 0, 0, 0);
            const int c0 = s0 + es * 32 + cc * 16;
            if (c0 + 15 > qrow0) {      // diagonal-crossing: mask (s <= q)
                const int rowabs = qrow0 + l15;          // q
                const int colbase = c0 + quad * 4;       // s of reg 0
#pragma unroll
                for (int r = 0; r < 4; ++r)
                    sf[r] = (colbase + r <= rowabs) ? sf[r] : -__builtin_inff();
            }
            u32 pk[2];
            pk[0] = pkbf(exp2f(sf[0]), exp2f(sf[1]));
            pk[1] = pkbf(exp2f(sf[2]), exp2f(sf[3]));
            *(uint2*)&Plds[jt & 1][(qs * 16 + l15) * 72 + es * 32 + cc * 16 + quad * 4]
                = *(const uint2*)pk;
        }
    };

    // ---- prologue: tile 0 ----
    stageV(0, 0);
    {
        bf16x8 kf0[4];
        loadK(0, kf0);
        computeP(0, kf0);
    }

    for (int it = 0; it < ntiles; ++it) {
        __syncthreads();                 // V(it), P(it) ready (vmcnt drained)
        const int buf = it & 1;
        const bool haveNext = (it + 1 < ntiles);
        const bool nextActive = haveNext && ((it + 1) * 64 <= qlim);
        const bool curActive = (it * 64 <= qlim);

        if (haveNext) stageV(buf ^ 1, it + 1);
        bf16x8 kf[4];
        if (nextActive) loadK(it + 1, kf);

        if (curActive) {
            // ---- O += P @ V ; l += P @ 1 ---- (two s-halves h)
#pragma unroll
            for (int h = 0; h < 2; ++h) {
                const bf16x8 pf = *(const bf16x8*)
                    &Plds[buf][(qs * 16 + l15) * 72 + h * 32 + quad * 8];
                accl = __builtin_amdgcn_mfma_f32_16x16x32_bf16(pf, ones, accl, 0, 0, 0);
#pragma unroll
                for (int nb = 0; nb < 8; ++nb) {
                    bf16x8 vf = *(const bf16x8*)
                        &Vlds[buf][(h * 16 + es * 8 + nb) * 512 + lane * 8];
                    acc[nb] = __builtin_amdgcn_mfma_f32_16x16x32_bf16(
                        pf, vf, acc[nb], 0, 0, 0);
                }
            }
        }

        if (nextActive) computeP(it + 1, kf);
    }

    // ---- epilogue: normalize by row sums ----
    float rl[4];
#pragma unroll
    for (int r = 0; r < 4; ++r) rl[r] = 1.0f / accl[r];
#pragma unroll
    for (int nb = 0; nb < 8; ++nb)
#pragma unroll
        for (int r = 0; r < 4; ++r) {
            const int row = qrow0 + quad * 4 + r;
            const int col = e0 + es * 128 + nb * 16 + l15;
            Out[(size_t)(bt0 + row) * 1024 + col] = acc[nb][r] * rl[r];
        }
}

// ----------------------------------------------------------------------------
extern "C" void kernel_launch(void* const* d_in, const int* in_sizes, int n_in,
                              void* d_out, int out_size, void* d_ws, size_t ws_size,
                              hipStream_t stream) {
    const float* x  = (const float*)d_in[0];   // [4,4096,1024]
    const float* Wk = (const float*)d_in[1];   // [64,1024]
    const float* Wq = (const float*)d_in[2];   // [64,1024]
    const float* Wv = (const float*)d_in[3];   // [1024,1024]

    const int nx  = in_sizes[0];
    const int nwk = in_sizes[1];
    const int nwq = in_sizes[2];
    const int nwv = in_sizes[3];

    u16* xb  = (u16*)d_ws;
    u16* Wkb = xb  + (size_t)nx;
    u16* Wqb = Wkb + (size_t)nwk;
    u16* Wvb = Wqb + (size_t)nwq;
    u16* Qf  = Wvb + (size_t)nwv;                    // 1024 btiles * 2 * 512
    u16* Kf  = Qf  + (size_t)1024 * 2 * 512;
    u16* Vf  = Kf  + (size_t)1024 * 2 * 512;         // 64 etiles * 512 * 512
    float* out = (float*)d_out;

    const float qscale = 0.125f * 1.44269504088896f; // fold 1/sqrt(H)*log2(e)

    cvt_x<<<nx / 2048, 256, 0, stream>>>(x, xb, nx);
    cvt_w<<<(nwk + nwq + nwv) / 2048, 256, 0, stream>>>(Wk, Wq, Wv,
                                                        Wkb, Wqb, Wvb, qscale);

    gemm_all<<<1152, 256, 0, stream>>>(xb, Wqb, Wkb, Wvb, Qf, Kf, Vf);

    attn_fa<<<dim3(128, 4), 1024, 0, stream>>>(Qf, Kf, Vf, out);
}

// Round 19
// 328.270 us; speedup vs baseline: 1.0374x; 1.0374x over previous
//
#include <hip/hip_runtime.h>
#include <hip/hip_bf16.h>

// ============================================================================
// Head: K=x@Wk^T, Q=x@Wq^T, V=x@Wv^T, causal softmax(QK^T/8)@V
// B=4, T=4096, D=1024, H=64. fp32 I/O, bf16 MFMA compute.
//
// R24 = R23 resubmit (round 18 died to broker capacity, never measured).
// R23 = R22 (verified 340.5us; R20 339.4 best; attn ~190, Mfma 21.4 /
// VALU 35.8 / Occ 37.3) + ONE schedule change: computeP(it+1) hoisted
// BEFORE PV(it); loadK moves one stage out (it+2) into persistent kfN.
//  Why: computeP's ~40-VALU tail (exp2+pack+mask+ds_write) sits on the
//  barrier edge — pure exposed convoy time (VALU is top pipe, ~43%
//  no-issue). Hoisted, it drains under PV's 18-MFMA stretch; K loads get
//  a full iteration of latency cover.
//  Safety: the R6 NaN is attributed to the asm cluster, NOT the reorder —
//  R11 corrupted WITHOUT the reorder (cluster only); R12+ pass without
//  the cluster. Guards: loadK(it+2)'s guard in iter it == computeP(it+2)'s
//  guard in iter it+1 (exact); Plds WAR separated by the top-of-iter
//  barrier. All else byte-identical to R22.
//
// FENCED (R6=NaN / R11=3.6e5): {v_cvt_pk_bf16_f32 asm, __builtin_amdgcn_exp2f,
// s_setprio} in attn_fa — register/LDS corruption at the 128-reg wall.
// Dead: V-in-registers (R10 spills); 64-row 4-wave blocks (R9 drain-out);
// more waves (R13/R14: +50% occupancy, 0% speedup); attn micro-opts
// converged (R13 0%, R15 +7%, R17 0%); gemm L3-BW theory (R20: -4us);
// gemm launch-bounds (R21/R22: no-op).
// ============================================================================

typedef __attribute__((ext_vector_type(8))) short bf16x8;   // 8 bf16, 4 VGPRs
typedef __attribute__((ext_vector_type(4))) float f32x4;

typedef unsigned short u16;
typedef unsigned int u32;

__device__ inline u16 f2bf(float f) {
    u32 u = __builtin_bit_cast(u32, f);
    u = (u + 0x7fff + ((u >> 16) & 1)) >> 16;   // RNE
    return (u16)u;
}

__device__ inline u32 pkbf(float a, float b) {  // bf16(a) | bf16(b)<<16
    return (u32)f2bf(a) | ((u32)f2bf(b) << 16);
}

__device__ inline void g2lds16(const void* g, void* l) {
    __builtin_amdgcn_global_load_lds(
        (const __attribute__((address_space(1))) unsigned int*)g,
        (__attribute__((address_space(3))) unsigned int*)l, 16, 0, 0);
}

// Fragment-tile addressing (16 rows x 32 k, 512 u16 = 1KB per tile):
//   element (r, k): u16 idx = ((r&15) + ((k>>3)&3)*16)*8 + (k&7)
// A-frag (m=lane&15, k=quad*8+j) and B-frag (n=lane&15, k=quad*8+j) reads are
// both "base + lane*16B" -> coalesced global / conflict-free LDS.

// ----------------------------------------------------------------------------
__global__ void cvt_x(const float* __restrict__ src, u16* __restrict__ dst,
                      int n) {
    const int i = (blockIdx.x * blockDim.x + threadIdx.x) * 8;
    if (i + 7 < n) {
        const float4 a = *(const float4*)(src + i);
        const float4 b = *(const float4*)(src + i + 4);
        u32 r[4];
        r[0] = pkbf(a.x, a.y);
        r[1] = pkbf(a.z, a.w);
        r[2] = pkbf(b.x, b.y);
        r[3] = pkbf(b.z, b.w);
        *(uint4*)(dst + i) = *(const uint4*)r;
    }
}

// Fused weight convert: Wk (1x), Wq (x 0.125*log2e), Wv (1x).
__global__ void cvt_w(const float* __restrict__ Wk, const float* __restrict__ Wq,
                      const float* __restrict__ Wv,
                      u16* __restrict__ Wkb, u16* __restrict__ Wqb,
                      u16* __restrict__ Wvb, float qscale) {
    const int i = (blockIdx.x * blockDim.x + threadIdx.x) * 8;
    const float* src; u16* dst; int j; float s = 1.0f;
    if (i < 65536)        { src = Wk; dst = Wkb; j = i; }
    else if (i < 131072)  { src = Wq; dst = Wqb; j = i - 65536; s = qscale; }
    else                  { src = Wv; dst = Wvb; j = i - 131072; }
    const float4 a = *(const float4*)(src + j);
    const float4 b = *(const float4*)(src + j + 4);
    u32 r[4];
    r[0] = pkbf(a.x * s, a.y * s);
    r[1] = pkbf(a.z * s, a.w * s);
    r[2] = pkbf(b.x * s, b.y * s);
    r[3] = pkbf(b.z * s, b.w * s);
    *(uint4*)(dst + j) = *(const uint4*)r;
}

// ----------------------------------------------------------------------------
// GEMM body: C = A[M][K] @ Bsel[N][K]^T, bf16, fp32 accum, 128x128, BK=64.
// lda = ldb = K = 1024. Outputs frag-tiled (MODE 1: Qf/Kf, MODE 2: Vf).
// ----------------------------------------------------------------------------
template <int MODE>
__device__ __forceinline__ void gemm_body(
    int m0, int n0,
    const u16* __restrict__ A,
    const u16* __restrict__ B0, const u16* __restrict__ B1, int nsplit,
    u16* __restrict__ D0, u16* __restrict__ D1,
    u16* Alds, u16* Blds)
{
    const int tid  = threadIdx.x;
    const int lane = tid & 63, w = tid >> 6;
    const int quad = lane >> 4, l15 = lane & 15;
    const int wr = w >> 1, wc = w & 1;
    const int mrow0 = wr * 64, ncol0 = wc * 64;

    f32x4 acc[4][4] = {};

    const int srow = (lane >> 3);
    const int scol = (lane & 7) * 8;

    for (int k0 = 0; k0 < 1024; k0 += 64) {
        __syncthreads();
#pragma unroll
        for (int c = 0; c < 4; ++c) {
            const int chunk = c * 4 + w;
            const int row = chunk * 8 + srow;
            const u16* ga = A + (size_t)(m0 + row) * 1024 + k0 + scol;
            g2lds16(ga, &Alds[chunk * 512]);
            const int brow = n0 + row;
            const u16* gb = (brow < nsplit ? B0 + (size_t)brow * 1024
                                           : B1 + (size_t)(brow - nsplit) * 1024)
                            + k0 + scol;
            g2lds16(gb, &Blds[chunk * 512]);
        }
        __syncthreads();

#pragma unroll
        for (int kk = 0; kk < 64; kk += 32) {
            bf16x8 af[4], bfr[4];
#pragma unroll
            for (int mb = 0; mb < 4; ++mb)
                af[mb] = *(const bf16x8*)&Alds[(mrow0 + mb * 16 + l15) * 64 + kk + quad * 8];
#pragma unroll
            for (int nb = 0; nb < 4; ++nb)
                bfr[nb] = *(const bf16x8*)&Blds[(ncol0 + nb * 16 + l15) * 64 + kk + quad * 8];
#pragma unroll
            for (int mb = 0; mb < 4; ++mb)
#pragma unroll
                for (int nb = 0; nb < 4; ++nb)
                    acc[mb][nb] = __builtin_amdgcn_mfma_f32_16x16x32_bf16(
                        af[mb], bfr[nb], acc[mb][nb], 0, 0, 0);
        }
    }

    // epilogue: C/D layout col=lane&15, row=quad*4+reg
#pragma unroll
    for (int mb = 0; mb < 4; ++mb)
#pragma unroll
        for (int nb = 0; nb < 4; ++nb)
#pragma unroll
            for (int r = 0; r < 4; ++r) {
                const int row = m0 + mrow0 + mb * 16 + quad * 4 + r;
                const int col = n0 + ncol0 + nb * 16 + l15;
                const u16 v = f2bf(acc[mb][nb][r]);
                if (MODE == 1) {
                    const int h = col & 63;
                    u16* dst = (col < 64) ? D0 : D1;
                    const size_t idx = (size_t)((row >> 4) * 2 + (h >> 5)) * 512
                                     + ((row & 15) + ((h >> 3) & 3) * 16) * 8
                                     + (h & 7);
                    dst[idx] = v;
                } else {
                    const size_t idx = (size_t)((row >> 4) * 512 + (col >> 5)) * 512
                                     + ((row & 15) + ((col >> 3) & 3) * 16) * 8
                                     + (col & 7);
                    D0[idx] = v;
                }
            }
}

// Combined GEMM dispatch: blocks [0,128) -> QK projection, [128,1152) -> Vt.
// MODE2 block->tile remap for XCD/L2 locality: g=dd&7, j=dd>>3,
// m0=(j&7)*128, n0=(g*16+(j>>3))*128.
__global__ __launch_bounds__(256, 3) void gemm_all(
    const u16* __restrict__ xb,
    const u16* __restrict__ Wqb, const u16* __restrict__ Wkb,
    const u16* __restrict__ Wvb,
    u16* __restrict__ Qf, u16* __restrict__ Kf, u16* __restrict__ Vf)
{
    __shared__ u16 Alds[128 * 64];
    __shared__ u16 Blds[128 * 64];
    const int d = blockIdx.x;
    if (d < 128) {
        gemm_body<1>(d * 128, 0, xb, Wqb, Wkb, 64, Qf, Kf, Alds, Blds);
    } else {
        const int dd = d - 128;
        const int g = dd & 7, j = dd >> 3;
        gemm_body<2>((j & 7) * 128, (g * 16 + (j >> 3)) * 128, Wvb, xb, xb,
                     1 << 30, Vf, nullptr, Alds, Blds);
    }
}

// ----------------------------------------------------------------------------
// Flash attention, no-max softmax, es-split P handoff, software-pipelined.
// grid (128,4) flat d: g=d>>4, qt = g<16 ? 31-g : g-16 (complementary pairs),
// e0 = ((d>>2)&3)*256, b = d&3. Block 1024 thr (16 waves): wave w ->
// qs=w>>1 (16 q rows), es=w&1. s-tile = 64: ntiles = 2qt+2.
// R23 iter order: barrier -> stageV(it+1) -> computeP(it+1) [tail drains
// under PV] -> loadK(it+2 -> kfN) -> PV(it).
// computeP uses SWAPPED mfma(K,Q): lane holds P[q=l15][s=quad*4+r] ->
// one ds_write_b64 per strip.
// ----------------------------------------------------------------------------
__global__ __launch_bounds__(1024, 4) void attn_fa(
    const u16* __restrict__ Qf,
    const u16* __restrict__ Kf,
    const u16* __restrict__ Vf,
    float* __restrict__ Out)
{
    __shared__ u16 Vlds[2][32 * 512];   // 2 x 32KB (e=256, s=64)
    __shared__ u16 Plds[2][128 * 72];   // 2 x 18KB block-shared P, row-pad 72

    const int tid  = threadIdx.x;
    const int lane = tid & 63, w = tid >> 6;      // w in [0,16)
    const int quad = lane >> 4, l15 = lane & 15;

    const int d  = blockIdx.y * 128 + blockIdx.x;
    const int g  = d >> 4;
    const int qt = (g < 16) ? (31 - g) : (g - 16);
    const int e0 = ((d >> 2) & 3) * 256;
    const int b  = d & 3;
    const int bt0 = b * 4096;

    const int qs = w >> 1, es = w & 1;            // qs in [0,8): 16 rows each
    const int qrow0 = qt * 128 + qs * 16;

    // Q A-frags (persistent, log2-domain scaled): one 16-row tile, K=64
    bf16x8 qf[2];
    {
        const int btile = (bt0 + qrow0) >> 4;
#pragma unroll
        for (int kk = 0; kk < 2; ++kk)
            qf[kk] = *(const bf16x8*)&Qf[(size_t)(btile * 2 + kk) * 512 + lane * 8];
    }

    // ones B-fragment for row-sum accumulation (bf16 1.0 = 0x3F80)
    const short o = (short)0x3F80;
    const bf16x8 ones = {o, o, o, o, o, o, o, o};

    f32x4 acc[8] = {};      // O accumulator [nb_e]
    f32x4 accl = {};        // row-sum accumulator

    const int ntiles = 2 * qt + 2;      // s-tiles of 64
    const int qlim = qrow0 + 15;        // wave active for tile it iff it*64 <= qlim

    // ---- stage V tile `it` (64 s-cols) into Vlds[buf]: 2KB per wave ----
    auto stageV = [&](int buf, int it) {
        const int ct0 = (bt0 >> 5) + it * 2;
#pragma unroll
        for (int h = 0; h < 2; ++h)
            g2lds16(&Vf[(size_t)(((e0 >> 4) + w) * 512 + ct0 + h) * 512 + lane * 8],
                    &Vlds[buf][(h * 16 + w) * 512]);
    };

    // ---- load this wave's K quarter for tile `jt` (4 x b128 global) ----
    auto loadK = [&](int jt, bf16x8* kf) {
#pragma unroll
        for (int cc = 0; cc < 2; ++cc)
#pragma unroll
            for (int kk = 0; kk < 2; ++kk) {
                const int kt = ((bt0 + jt * 64 + es * 32 + cc * 16) >> 4) * 2 + kk;
                kf[cc * 2 + kk] = *(const bf16x8*)&Kf[(size_t)kt * 512 + lane * 8];
            }
    };

    // ---- compute this wave's (16q x 32s) strip of P(jt) into Plds[jt&1] ----
    // SWAPPED mfma(K,Q): D[m=s][n=q] -> lane (quad,l15) holds
    // P[q=qrow0+l15][s=c0+quad*4+r], 4 consecutive s in one Plds row.
    auto computeP = [&](int jt, const bf16x8* kf) {
        const int s0 = jt * 64;
#pragma unroll
        for (int cc = 0; cc < 2; ++cc) {
            f32x4 sf = {};
#pragma unroll
            for (int kk = 0; kk < 2; ++kk)
                sf = __builtin_amdgcn_mfma_f32_16x16x32_bf16(
                    kf[cc * 2 + kk], qf[kk], sf, 0, 0, 0);
            const int c0 = s0 + es * 32 + cc * 16;
            if (c0 + 15 > qrow0) {      // diagonal-crossing: mask (s <= q)
                const int rowabs = qrow0 + l15;          // q
                const int colbase = c0 + quad * 4;       // s of reg 0
#pragma unroll
                for (int r = 0; r < 4; ++r)
                    sf[r] = (colbase + r <= rowabs) ? sf[r] : -__builtin_inff();
            }
            u32 pk[2];
            pk[0] = pkbf(exp2f(sf[0]), exp2f(sf[1]));
            pk[1] = pkbf(exp2f(sf[2]), exp2f(sf[3]));
            *(uint2*)&Plds[jt & 1][(qs * 16 + l15) * 72 + es * 32 + cc * 16 + quad * 4]
                = *(const uint2*)pk;
        }
    };

    // ---- prologue: tile 0, and K for tile 1 into persistent kfN ----
    stageV(0, 0);
    {
        bf16x8 kf0[4];
        loadK(0, kf0);
        computeP(0, kf0);
    }
    bf16x8 kfN[4];
    if (ntiles > 1 && 64 <= qlim) loadK(1, kfN);

    for (int it = 0; it < ntiles; ++it) {
        __syncthreads();                 // V(it), P(it) ready (vmcnt drained)
        const int buf = it & 1;
        const bool haveNext   = (it + 1 < ntiles);
        const bool nextActive = haveNext && ((it + 1) * 64 <= qlim);
        const bool next2Active = (it + 2 < ntiles) && ((it + 2) * 64 <= qlim);
        const bool curActive  = (it * 64 <= qlim);

        if (haveNext) stageV(buf ^ 1, it + 1);
        // P(it+1) FIRST: its exp2+pack+ds_write tail drains under PV's MFMA
        // stretch instead of sitting on the barrier edge.
        if (nextActive) computeP(it + 1, kfN);
        if (next2Active) loadK(it + 2, kfN);   // WAR on kfN after last use

        if (curActive) {
            // ---- O += P @ V ; l += P @ 1 ---- (two s-halves h)
#pragma unroll
            for (int h = 0; h < 2; ++h) {
                const bf16x8 pf = *(const bf16x8*)
                    &Plds[buf][(qs * 16 + l15) * 72 + h * 32 + quad * 8];
                accl = __builtin_amdgcn_mfma_f32_16x16x32_bf16(pf, ones, accl, 0, 0, 0);
#pragma unroll
                for (int nb = 0; nb < 8; ++nb) {
                    bf16x8 vf = *(const bf16x8*)
                        &Vlds[buf][(h * 16 + es * 8 + nb) * 512 + lane * 8];
                    acc[nb] = __builtin_amdgcn_mfma_f32_16x16x32_bf16(
                        pf, vf, acc[nb], 0, 0, 0);
                }
            }
        }
    }

    // ---- epilogue: normalize by row sums ----
    float rl[4];
#pragma unroll
    for (int r = 0; r < 4; ++r) rl[r] = 1.0f / accl[r];
#pragma unroll
    for (int nb = 0; nb < 8; ++nb)
#pragma unroll
        for (int r = 0; r < 4; ++r) {
            const int row = qrow0 + quad * 4 + r;
            const int col = e0 + es * 128 + nb * 16 + l15;
            Out[(size_t)(bt0 + row) * 1024 + col] = acc[nb][r] * rl[r];
        }
}

// ----------------------------------------------------------------------------
extern "C" void kernel_launch(void* const* d_in, const int* in_sizes, int n_in,
                              void* d_out, int out_size, void* d_ws, size_t ws_size,
                              hipStream_t stream) {
    const float* x  = (const float*)d_in[0];   // [4,4096,1024]
    const float* Wk = (const float*)d_in[1];   // [64,1024]
    const float* Wq = (const float*)d_in[2];   // [64,1024]
    const float* Wv = (const float*)d_in[3];   // [1024,1024]

    const int nx  = in_sizes[0];
    const int nwk = in_sizes[1];
    const int nwq = in_sizes[2];
    const int nwv = in_sizes[3];

    u16* xb  = (u16*)d_ws;
    u16* Wkb = xb  + (size_t)nx;
    u16* Wqb = Wkb + (size_t)nwk;
    u16* Wvb = Wqb + (size_t)nwq;
    u16* Qf  = Wvb + (size_t)nwv;                    // 1024 btiles * 2 * 512
    u16* Kf  = Qf  + (size_t)1024 * 2 * 512;
    u16* Vf  = Kf  + (size_t)1024 * 2 * 512;         // 64 etiles * 512 * 512
    float* out = (float*)d_out;

    const float qscale = 0.125f * 1.44269504088896f; // fold 1/sqrt(H)*log2(e)

    cvt_x<<<nx / 2048, 256, 0, stream>>>(x, xb, nx);
    cvt_w<<<(nwk + nwq + nwv) / 2048, 256, 0, stream>>>(Wk, Wq, Wv,
                                                        Wkb, Wqb, Wvb, qscale);

    gemm_all<<<1152, 256, 0, stream>>>(xb, Wqb, Wkb, Wvb, Qf, Kf, Vf);

    attn_fa<<<dim3(128, 4), 1024, 0, stream>>>(Qf, Kf, Vf, out);
}

// Round 21
// 328.100 us; speedup vs baseline: 1.0379x; 1.0005x over previous
//
#include <hip/hip_runtime.h>
#include <hip/hip_bf16.h>

// ============================================================================
// Head: K=x@Wk^T, Q=x@Wq^T, V=x@Wv^T, causal softmax(QK^T/8)@V
// B=4, T=4096, D=1024, H=64. fp32 I/O, bf16 MFMA compute.
//
// FINAL (verified R24 @ Round 19: 328.3us; attn 180.4, Mfma 22.3 / VALU 37.5).
// Session ladder (351.6 -> 328.3, all harness-verified):
//  * R12: vectorized cvt_x/cvt_w (8 elem/thr, uint4 stores)
//  * R13/14: 16-wave blocks, wave=16 q-rows (occ 24->37)
//  * R15/16: s-tile 64 (half the iterations; attn 200->186)
//  * R17/19: swapped mfma(K,Q) -> b64 P-writes (neutral; kept: fewer stores)
//  * R20: MODE2 XCD/L2 remap (+1us)
//  * R23/24: computeP(it+1) hoisted before PV(it), loadK(it+2)->kfN
//    (exp2+pack+ds_write tail drains under PV's MFMA stretch; attn 190->180)
//
// NOT at HW roofline (Mfma 22%, HBM 6.7%): remaining headroom requires the
// FENCED inline-asm machinery (counted vmcnt / cvt_pk / setprio — corrupted
// state twice at the 128-reg wall: R6 NaN, R11 3.6e5) or a full 8-phase
// rewrite. All plain-C levers measured: occupancy (0%), tile (+7%),
// b64-writes (0%), XCD remap (+1%), launch bounds (0%), hoist (+3.3%).
// ============================================================================

typedef __attribute__((ext_vector_type(8))) short bf16x8;   // 8 bf16, 4 VGPRs
typedef __attribute__((ext_vector_type(4))) float f32x4;

typedef unsigned short u16;
typedef unsigned int u32;

__device__ inline u16 f2bf(float f) {
    u32 u = __builtin_bit_cast(u32, f);
    u = (u + 0x7fff + ((u >> 16) & 1)) >> 16;   // RNE
    return (u16)u;
}

__device__ inline u32 pkbf(float a, float b) {  // bf16(a) | bf16(b)<<16
    return (u32)f2bf(a) | ((u32)f2bf(b) << 16);
}

__device__ inline void g2lds16(const void* g, void* l) {
    __builtin_amdgcn_global_load_lds(
        (const __attribute__((address_space(1))) unsigned int*)g,
        (__attribute__((address_space(3))) unsigned int*)l, 16, 0, 0);
}

// Fragment-tile addressing (16 rows x 32 k, 512 u16 = 1KB per tile):
//   element (r, k): u16 idx = ((r&15) + ((k>>3)&3)*16)*8 + (k&7)
// A-frag (m=lane&15, k=quad*8+j) and B-frag (n=lane&15, k=quad*8+j) reads are
// both "base + lane*16B" -> coalesced global / conflict-free LDS.

// ----------------------------------------------------------------------------
__global__ void cvt_x(const float* __restrict__ src, u16* __restrict__ dst,
                      int n) {
    const int i = (blockIdx.x * blockDim.x + threadIdx.x) * 8;
    if (i + 7 < n) {
        const float4 a = *(const float4*)(src + i);
        const float4 b = *(const float4*)(src + i + 4);
        u32 r[4];
        r[0] = pkbf(a.x, a.y);
        r[1] = pkbf(a.z, a.w);
        r[2] = pkbf(b.x, b.y);
        r[3] = pkbf(b.z, b.w);
        *(uint4*)(dst + i) = *(const uint4*)r;
    }
}

// Fused weight convert: Wk (1x), Wq (x 0.125*log2e), Wv (1x).
__global__ void cvt_w(const float* __restrict__ Wk, const float* __restrict__ Wq,
                      const float* __restrict__ Wv,
                      u16* __restrict__ Wkb, u16* __restrict__ Wqb,
                      u16* __restrict__ Wvb, float qscale) {
    const int i = (blockIdx.x * blockDim.x + threadIdx.x) * 8;
    const float* src; u16* dst; int j; float s = 1.0f;
    if (i < 65536)        { src = Wk; dst = Wkb; j = i; }
    else if (i < 131072)  { src = Wq; dst = Wqb; j = i - 65536; s = qscale; }
    else                  { src = Wv; dst = Wvb; j = i - 131072; }
    const float4 a = *(const float4*)(src + j);
    const float4 b = *(const float4*)(src + j + 4);
    u32 r[4];
    r[0] = pkbf(a.x * s, a.y * s);
    r[1] = pkbf(a.z * s, a.w * s);
    r[2] = pkbf(b.x * s, b.y * s);
    r[3] = pkbf(b.z * s, b.w * s);
    *(uint4*)(dst + j) = *(const uint4*)r;
}

// ----------------------------------------------------------------------------
// GEMM body: C = A[M][K] @ Bsel[N][K]^T, bf16, fp32 accum, 128x128, BK=64.
// lda = ldb = K = 1024. Outputs frag-tiled (MODE 1: Qf/Kf, MODE 2: Vf).
// ----------------------------------------------------------------------------
template <int MODE>
__device__ __forceinline__ void gemm_body(
    int m0, int n0,
    const u16* __restrict__ A,
    const u16* __restrict__ B0, const u16* __restrict__ B1, int nsplit,
    u16* __restrict__ D0, u16* __restrict__ D1,
    u16* Alds, u16* Blds)
{
    const int tid  = threadIdx.x;
    const int lane = tid & 63, w = tid >> 6;
    const int quad = lane >> 4, l15 = lane & 15;
    const int wr = w >> 1, wc = w & 1;
    const int mrow0 = wr * 64, ncol0 = wc * 64;

    f32x4 acc[4][4] = {};

    const int srow = (lane >> 3);
    const int scol = (lane & 7) * 8;

    for (int k0 = 0; k0 < 1024; k0 += 64) {
        __syncthreads();
#pragma unroll
        for (int c = 0; c < 4; ++c) {
            const int chunk = c * 4 + w;
            const int row = chunk * 8 + srow;
            const u16* ga = A + (size_t)(m0 + row) * 1024 + k0 + scol;
            g2lds16(ga, &Alds[chunk * 512]);
            const int brow = n0 + row;
            const u16* gb = (brow < nsplit ? B0 + (size_t)brow * 1024
                                           : B1 + (size_t)(brow - nsplit) * 1024)
                            + k0 + scol;
            g2lds16(gb, &Blds[chunk * 512]);
        }
        __syncthreads();

#pragma unroll
        for (int kk = 0; kk < 64; kk += 32) {
            bf16x8 af[4], bfr[4];
#pragma unroll
            for (int mb = 0; mb < 4; ++mb)
                af[mb] = *(const bf16x8*)&Alds[(mrow0 + mb * 16 + l15) * 64 + kk + quad * 8];
#pragma unroll
            for (int nb = 0; nb < 4; ++nb)
                bfr[nb] = *(const bf16x8*)&Blds[(ncol0 + nb * 16 + l15) * 64 + kk + quad * 8];
#pragma unroll
            for (int mb = 0; mb < 4; ++mb)
#pragma unroll
                for (int nb = 0; nb < 4; ++nb)
                    acc[mb][nb] = __builtin_amdgcn_mfma_f32_16x16x32_bf16(
                        af[mb], bfr[nb], acc[mb][nb], 0, 0, 0);
        }
    }

    // epilogue: C/D layout col=lane&15, row=quad*4+reg
#pragma unroll
    for (int mb = 0; mb < 4; ++mb)
#pragma unroll
        for (int nb = 0; nb < 4; ++nb)
#pragma unroll
            for (int r = 0; r < 4; ++r) {
                const int row = m0 + mrow0 + mb * 16 + quad * 4 + r;
                const int col = n0 + ncol0 + nb * 16 + l15;
                const u16 v = f2bf(acc[mb][nb][r]);
                if (MODE == 1) {
                    const int h = col & 63;
                    u16* dst = (col < 64) ? D0 : D1;
                    const size_t idx = (size_t)((row >> 4) * 2 + (h >> 5)) * 512
                                     + ((row & 15) + ((h >> 3) & 3) * 16) * 8
                                     + (h & 7);
                    dst[idx] = v;
                } else {
                    const size_t idx = (size_t)((row >> 4) * 512 + (col >> 5)) * 512
                                     + ((row & 15) + ((col >> 3) & 3) * 16) * 8
                                     + (col & 7);
                    D0[idx] = v;
                }
            }
}

// Combined GEMM dispatch: blocks [0,128) -> QK projection, [128,1152) -> Vt.
// MODE2 block->tile remap for XCD/L2 locality: g=dd&7, j=dd>>3,
// m0=(j&7)*128, n0=(g*16+(j>>3))*128.
__global__ __launch_bounds__(256, 3) void gemm_all(
    const u16* __restrict__ xb,
    const u16* __restrict__ Wqb, const u16* __restrict__ Wkb,
    const u16* __restrict__ Wvb,
    u16* __restrict__ Qf, u16* __restrict__ Kf, u16* __restrict__ Vf)
{
    __shared__ u16 Alds[128 * 64];
    __shared__ u16 Blds[128 * 64];
    const int d = blockIdx.x;
    if (d < 128) {
        gemm_body<1>(d * 128, 0, xb, Wqb, Wkb, 64, Qf, Kf, Alds, Blds);
    } else {
        const int dd = d - 128;
        const int g = dd & 7, j = dd >> 3;
        gemm_body<2>((j & 7) * 128, (g * 16 + (j >> 3)) * 128, Wvb, xb, xb,
                     1 << 30, Vf, nullptr, Alds, Blds);
    }
}

// ----------------------------------------------------------------------------
// Flash attention, no-max softmax, es-split P handoff, software-pipelined.
// grid (128,4) flat d: g=d>>4, qt = g<16 ? 31-g : g-16 (complementary pairs),
// e0 = ((d>>2)&3)*256, b = d&3. Block 1024 thr (16 waves): wave w ->
// qs=w>>1 (16 q rows), es=w&1. s-tile = 64: ntiles = 2qt+2.
// Iter order: barrier -> stageV(it+1) -> computeP(it+1) [tail drains under
// PV] -> loadK(it+2 -> kfN) -> PV(it).
// computeP uses SWAPPED mfma(K,Q): lane holds P[q=l15][s=quad*4+r] ->
// one ds_write_b64 per strip.
// ----------------------------------------------------------------------------
__global__ __launch_bounds__(1024, 4) void attn_fa(
    const u16* __restrict__ Qf,
    const u16* __restrict__ Kf,
    const u16* __restrict__ Vf,
    float* __restrict__ Out)
{
    __shared__ u16 Vlds[2][32 * 512];   // 2 x 32KB (e=256, s=64)
    __shared__ u16 Plds[2][128 * 72];   // 2 x 18KB block-shared P, row-pad 72

    const int tid  = threadIdx.x;
    const int lane = tid & 63, w = tid >> 6;      // w in [0,16)
    const int quad = lane >> 4, l15 = lane & 15;

    const int d  = blockIdx.y * 128 + blockIdx.x;
    const int g  = d >> 4;
    const int qt = (g < 16) ? (31 - g) : (g - 16);
    const int e0 = ((d >> 2) & 3) * 256;
    const int b  = d & 3;
    const int bt0 = b * 4096;

    const int qs = w >> 1, es = w & 1;            // qs in [0,8): 16 rows each
    const int qrow0 = qt * 128 + qs * 16;

    // Q A-frags (persistent, log2-domain scaled): one 16-row tile, K=64
    bf16x8 qf[2];
    {
        const int btile = (bt0 + qrow0) >> 4;
#pragma unroll
        for (int kk = 0; kk < 2; ++kk)
            qf[kk] = *(const bf16x8*)&Qf[(size_t)(btile * 2 + kk) * 512 + lane * 8];
    }

    // ones B-fragment for row-sum accumulation (bf16 1.0 = 0x3F80)
    const short o = (short)0x3F80;
    const bf16x8 ones = {o, o, o, o, o, o, o, o};

    f32x4 acc[8] = {};      // O accumulator [nb_e]
    f32x4 accl = {};        // row-sum accumulator

    const int ntiles = 2 * qt + 2;      // s-tiles of 64
    const int qlim = qrow0 + 15;        // wave active for tile it iff it*64 <= qlim

    // ---- stage V tile `it` (64 s-cols) into Vlds[buf]: 2KB per wave ----
    auto stageV = [&](int buf, int it) {
        const int ct0 = (bt0 >> 5) + it * 2;
#pragma unroll
        for (int h = 0; h < 2; ++h)
            g2lds16(&Vf[(size_t)(((e0 >> 4) + w) * 512 + ct0 + h) * 512 + lane * 8],
                    &Vlds[buf][(h * 16 + w) * 512]);
    };

    // ---- load this wave's K quarter for tile `jt` (4 x b128 global) ----
    auto loadK = [&](int jt, bf16x8* kf) {
#pragma unroll
        for (int cc = 0; cc < 2; ++cc)
#pragma unroll
            for (int kk = 0; kk < 2; ++kk) {
                const int kt = ((bt0 + jt * 64 + es * 32 + cc * 16) >> 4) * 2 + kk;
                kf[cc * 2 + kk] = *(const bf16x8*)&Kf[(size_t)kt * 512 + lane * 8];
            }
    };

    // ---- compute this wave's (16q x 32s) strip of P(jt) into Plds[jt&1] ----
    // SWAPPED mfma(K,Q): D[m=s][n=q] -> lane (quad,l15) holds
    // P[q=qrow0+l15][s=c0+quad*4+r], 4 consecutive s in one Plds row.
    auto computeP = [&](int jt, const bf16x8* kf) {
        const int s0 = jt * 64;
#pragma unroll
        for (int cc = 0; cc < 2; ++cc) {
            f32x4 sf = {};
#pragma unroll
            for (int kk = 0; kk < 2; ++kk)
                sf = __builtin_amdgcn_mfma_f32_16x16x32_bf16(
                    kf[cc * 2 + kk], qf[kk], sf, 0, 0, 0);
            const int c0 = s0 + es * 32 + cc * 16;
            if (c0 + 15 > qrow0) {      // diagonal-crossing: mask (s <= q)
                const int rowabs = qrow0 + l15;          // q
                const int colbase = c0 + quad * 4;       // s of reg 0
#pragma unroll
                for (int r = 0; r < 4; ++r)
                    sf[r] = (colbase + r <= rowabs) ? sf[r] : -__builtin_inff();
            }
            u32 pk[2];
            pk[0] = pkbf(exp2f(sf[0]), exp2f(sf[1]));
            pk[1] = pkbf(exp2f(sf[2]), exp2f(sf[3]));
            *(uint2*)&Plds[jt & 1][(qs * 16 + l15) * 72 + es * 32 + cc * 16 + quad * 4]
                = *(const uint2*)pk;
        }
    };

    // ---- prologue: tile 0, and K for tile 1 into persistent kfN ----
    stageV(0, 0);
    {
        bf16x8 kf0[4];
        loadK(0, kf0);
        computeP(0, kf0);
    }
    bf16x8 kfN[4];
    if (ntiles > 1 && 64 <= qlim) loadK(1, kfN);

    for (int it = 0; it < ntiles; ++it) {
        __syncthreads();                 // V(it), P(it) ready (vmcnt drained)
        const int buf = it & 1;
        const bool haveNext   = (it + 1 < ntiles);
        const bool nextActive = haveNext && ((it + 1) * 64 <= qlim);
        const bool next2Active = (it + 2 < ntiles) && ((it + 2) * 64 <= qlim);
        const bool curActive  = (it * 64 <= qlim);

        if (haveNext) stageV(buf ^ 1, it + 1);
        // P(it+1) FIRST: its exp2+pack+ds_write tail drains under PV's MFMA
        // stretch instead of sitting on the barrier edge.
        if (nextActive) computeP(it + 1, kfN);
        if (next2Active) loadK(it + 2, kfN);   // WAR on kfN after last use

        if (curActive) {
            // ---- O += P @ V ; l += P @ 1 ---- (two s-halves h)
#pragma unroll
            for (int h = 0; h < 2; ++h) {
                const bf16x8 pf = *(const bf16x8*)
                    &Plds[buf][(qs * 16 + l15) * 72 + h * 32 + quad * 8];
                accl = __builtin_amdgcn_mfma_f32_16x16x32_bf16(pf, ones, accl, 0, 0, 0);
#pragma unroll
                for (int nb = 0; nb < 8; ++nb) {
                    bf16x8 vf = *(const bf16x8*)
                        &Vlds[buf][(h * 16 + es * 8 + nb) * 512 + lane * 8];
                    acc[nb] = __builtin_amdgcn_mfma_f32_16x16x32_bf16(
                        pf, vf, acc[nb], 0, 0, 0);
                }
            }
        }
    }

    // ---- epilogue: normalize by row sums ----
    float rl[4];
#pragma unroll
    for (int r = 0; r < 4; ++r) rl[r] = 1.0f / accl[r];
#pragma unroll
    for (int nb = 0; nb < 8; ++nb)
#pragma unroll
        for (int r = 0; r < 4; ++r) {
            const int row = qrow0 + quad * 4 + r;
            const int col = e0 + es * 128 + nb * 16 + l15;
            Out[(size_t)(bt0 + row) * 1024 + col] = acc[nb][r] * rl[r];
        }
}

// ----------------------------------------------------------------------------
extern "C" void kernel_launch(void* const* d_in, const int* in_sizes, int n_in,
                              void* d_out, int out_size, void* d_ws, size_t ws_size,
                              hipStream_t stream) {
    const float* x  = (const float*)d_in[0];   // [4,4096,1024]
    const float* Wk = (const float*)d_in[1];   // [64,1024]
    const float* Wq = (const float*)d_in[2];   // [64,1024]
    const float* Wv = (const float*)d_in[3];   // [1024,1024]

    const int nx  = in_sizes[0];
    const int nwk = in_sizes[1];
    const int nwq = in_sizes[2];
    const int nwv = in_sizes[3];

    u16* xb  = (u16*)d_ws;
    u16* Wkb = xb  + (size_t)nx;
    u16* Wqb = Wkb + (size_t)nwk;
    u16* Wvb = Wqb + (size_t)nwq;
    u16* Qf  = Wvb + (size_t)nwv;                    // 1024 btiles * 2 * 512
    u16* Kf  = Qf  + (size_t)1024 * 2 * 512;
    u16* Vf  = Kf  + (size_t)1024 * 2 * 512;         // 64 etiles * 512 * 512
    float* out = (float*)d_out;

    const float qscale = 0.125f * 1.44269504088896f; // fold 1/sqrt(H)*log2(e)

    cvt_x<<<nx / 2048, 256, 0, stream>>>(x, xb, nx);
    cvt_w<<<(nwk + nwq + nwv) / 2048, 256, 0, stream>>>(Wk, Wq, Wv,
                                                        Wkb, Wqb, Wvb, qscale);

    gemm_all<<<1152, 256, 0, stream>>>(xb, Wqb, Wkb, Wvb, Qf, Kf, Vf);

    attn_fa<<<dim3(128, 4), 1024, 0, stream>>>(Qf, Kf, Vf, out);
}